// Round 9
// baseline (80.551 us; speedup 1.0000x reference)
//
#include <hip/hip_runtime.h>
#include <math.h>

#define NB 8
#define ND 64
#define NS 512
#define JT 8
#define PAD 68

typedef __attribute__((ext_vector_type(8))) short bf16x8;
typedef __attribute__((ext_vector_type(4))) float f32x4;
typedef __attribute__((ext_vector_type(4))) unsigned short us4;
typedef __attribute__((ext_vector_type(8))) unsigned short us8;

__device__ __forceinline__ unsigned short f2bf(float f) {
    unsigned int u = __float_as_uint(f);
    unsigned int r = (u + 0x7FFFu + ((u >> 16) & 1u)) >> 16;   // RNE
    return (unsigned short)r;
}

// ---------------------------------------------------------------------------
// Kernel 1 (R5-validated): blocks x<64: a/b GEMM -> a_bf,b_bf,na,nb.
// blocks x>=64: x->x_bf + rs rowsums; first init block zeroes the counters.
// ---------------------------------------------------------------------------
__global__ __launch_bounds__(256) void k_ab(const float* __restrict__ x,
                                            const float* __restrict__ W,
                                            unsigned short* __restrict__ a_bf,
                                            unsigned short* __restrict__ b_bf,
                                            float* __restrict__ na,
                                            float* __restrict__ nb,
                                            unsigned short* __restrict__ x_bf,
                                            float* __restrict__ rs,
                                            int* __restrict__ cnt) {
    __shared__ __align__(16) float Ww_t[ND][PAD];
    __shared__ __align__(16) float Wh_t[ND][PAD];
    __shared__ __align__(16) float x_t[JT][PAD];

    int b  = blockIdx.y;
    int bx = blockIdx.x;
    int t  = threadIdx.x;

    if (bx >= NS / JT) {
        int e    = bx - NS / JT;          // 0..7
        int wv   = t >> 6;
        int lane = t & 63;
        if (bx == NS / JT && t < 8) cnt[b * 8 + t] = 0;   // zero counters each call
#pragma unroll
        for (int rr = 0; rr < 2; ++rr) {
            int d = e * 8 + wv * 2 + rr;
            const float4* xr4 = (const float4*)(x + ((size_t)(b * ND + d)) * NS);
            float4 v0 = xr4[2 * lane];
            float4 v1 = xr4[2 * lane + 1];
            float s = v0.x + v0.y + v0.z + v0.w + v1.x + v1.y + v1.z + v1.w;
#pragma unroll
            for (int m = 32; m >= 1; m >>= 1) s += __shfl_xor(s, m, 64);
            us8 h;
            h[0] = f2bf(v0.x); h[1] = f2bf(v0.y); h[2] = f2bf(v0.z); h[3] = f2bf(v0.w);
            h[4] = f2bf(v1.x); h[5] = f2bf(v1.y); h[6] = f2bf(v1.z); h[7] = f2bf(v1.w);
            *(us8*)(x_bf + ((size_t)(b * ND + d)) * NS + lane * 8) = h;
            if (lane == 0) rs[b * ND + d] = s;
        }
        return;
    }

    int j0 = bx * JT;
#pragma unroll
    for (int r = 0; r < 16; ++r) {
        int e = t + r * 256;
        int d = e >> 6, k = e & 63;
        Ww_t[k][d] = W[e];
        Wh_t[k][d] = W[4096 + e];
    }
#pragma unroll
    for (int r = 0; r < 2; ++r) {
        int e = t + r * 256;
        int j = e & 7, d = e >> 3;
        x_t[j][d] = x[((size_t)(b * ND) + d) * NS + j0 + j];
    }
    __syncthreads();

    int k  = t & 63;
    int jq = t >> 6;
    const float4* wa4 = (const float4*)&Ww_t[k][0];
    const float4* wh4 = (const float4*)&Wh_t[k][0];
    const float4* xa4 = (const float4*)&x_t[jq][0];
    const float4* xb4 = (const float4*)&x_t[jq + 4][0];

    float aa0 = 0.f, ba0 = 0.f, aa1 = 0.f, ba1 = 0.f;
#pragma unroll
    for (int d4 = 0; d4 < 16; ++d4) {
        float4 wa = wa4[d4], wh = wh4[d4];
        float4 xa = xa4[d4], xb = xb4[d4];
        aa0 = fmaf(xa.x, wa.x, fmaf(xa.y, wa.y, fmaf(xa.z, wa.z, fmaf(xa.w, wa.w, aa0))));
        ba0 = fmaf(xa.x, wh.x, fmaf(xa.y, wh.y, fmaf(xa.z, wh.z, fmaf(xa.w, wh.w, ba0))));
        aa1 = fmaf(xb.x, wa.x, fmaf(xb.y, wa.y, fmaf(xb.z, wa.z, fmaf(xb.w, wa.w, aa1))));
        ba1 = fmaf(xb.x, wh.x, fmaf(xb.y, wh.y, fmaf(xb.z, wh.z, fmaf(xb.w, wh.w, ba1))));
    }
    size_t r0 = ((size_t)b * NS + j0 + jq) * ND + k;
    size_t r1 = ((size_t)b * NS + j0 + jq + 4) * ND + k;
    a_bf[r0] = f2bf(aa0);  a_bf[r1] = f2bf(aa1);
    b_bf[r0] = f2bf(ba0);  b_bf[r1] = f2bf(ba1);

    float sa0 = aa0 * aa0, sa1 = aa1 * aa1, sb0 = ba0 * ba0, sb1 = ba1 * ba1;
#pragma unroll
    for (int m = 32; m >= 1; m >>= 1) {
        sa0 += __shfl_xor(sa0, m, 64);
        sa1 += __shfl_xor(sa1, m, 64);
        sb0 += __shfl_xor(sb0, m, 64);
        sb1 += __shfl_xor(sb1, m, 64);
    }
    if (k == 0) {
        na[b * NS + j0 + jq]     = sa0;
        na[b * NS + j0 + jq + 4] = sa1;
        nb[b * NS + j0 + jq]     = sb0;
        nb[b * NS + j0 + jq + 4] = sb1;
    }
}

// ---------------------------------------------------------------------------
// Kernel 2 (R5 k_c + last-block-reduces): per live 64x64 (ti,u) tile compute
// the part-tile (disjoint stores), then atomic-count per (b,ti); the LAST
// arriving block reduces rs + part[ti..7] into out. Deterministic: fixed
// ascending-u sum order regardless of arrival order.
// ---------------------------------------------------------------------------
__global__ __launch_bounds__(256) void k_c(const unsigned short* __restrict__ x_bf,
                                           const unsigned short* __restrict__ a_bf,
                                           const unsigned short* __restrict__ b_bf,
                                           const float* __restrict__ na,
                                           const float* __restrict__ nb,
                                           const float* __restrict__ rs,
                                           float* __restrict__ part,
                                           int* __restrict__ cnt,
                                           float* __restrict__ out) {
    __shared__ unsigned short wm_lds[64 * 64];
    __shared__ int is_last;

    int b = blockIdx.y;
    int v = blockIdx.x;
    int u = 0;
    while ((u + 1) * (u + 2) / 2 <= v) ++u;   // w-tile index
    int ti = v - u * (u + 1) / 2;             // i-tile index (ti <= u)
    int i0 = ti * 64, w0 = u * 64;

    int t = threadIdx.x;
    int lane = t & 63, wv = t >> 6;
    int c = lane & 15, g = lane >> 4;

    // --- fragment loads ---
    bf16x8 afrag[2], bfrag[4][2], xfrag[4][2];
    {
        const unsigned short* bb = b_bf + ((size_t)(b * NS + w0 + 16 * wv + c)) * ND + g * 8;
        afrag[0] = *(const bf16x8*)(bb);
        afrag[1] = *(const bf16x8*)(bb + 32);
    }
#pragma unroll
    for (int n = 0; n < 4; ++n) {
        const unsigned short* aa = a_bf + ((size_t)(b * NS + i0 + 16 * n + c)) * ND + g * 8;
        bfrag[n][0] = *(const bf16x8*)(aa);
        bfrag[n][1] = *(const bf16x8*)(aa + 32);
    }
#pragma unroll
    for (int nd = 0; nd < 4; ++nd) {
        const unsigned short* xx = x_bf + ((size_t)(b * ND + 16 * nd + c)) * NS + w0 + 8 * g;
        xfrag[nd][0] = *(const bf16x8*)(xx);
        xfrag[nd][1] = *(const bf16x8*)(xx + 32);
    }
    float nbv[4], nav[4];
#pragma unroll
    for (int r = 0; r < 4; ++r) nbv[r] = nb[b * NS + w0 + 16 * wv + 4 * g + r];
#pragma unroll
    for (int n = 0; n < 4; ++n) nav[n] = na[b * NS + i0 + 16 * n + c];

    // --- GEMM1 + wm -> LDS ---
    int wbase = w0 + 16 * wv + 4 * g;
#pragma unroll
    for (int n = 0; n < 4; ++n) {
        f32x4 acc = {0.f, 0.f, 0.f, 0.f};
        acc = __builtin_amdgcn_mfma_f32_16x16x32_bf16(afrag[0], bfrag[n][0], acc, 0, 0, 0);
        acc = __builtin_amdgcn_mfma_f32_16x16x32_bf16(afrag[1], bfrag[n][1], acc, 0, 0, 0);
        int i_loc  = 16 * n + c;
        int i_glob = i0 + i_loc;
        us4 pk;
#pragma unroll
        for (int r = 0; r < 4; ++r) {
            float s2 = nav[n] + nbv[r] + 2.f * acc[r];
            float val = (i_glob <= wbase + r) ? -sqrtf(fmaxf(s2, 0.f)) : 0.f;
            pk[r] = f2bf(val);
        }
        int wblk = 2 * wv + (g >> 1);
        int hidx = i_loc * 64 + ((wblk ^ (i_loc & 7)) << 3) + 4 * (g & 1);
        *(us4*)(&wm_lds[hidx]) = pk;
    }
    __syncthreads();

    // --- GEMM2: partial c^T tile, disjoint float4 stores ---
    bf16x8 a2[2];
    {
        int il = 16 * wv + c;
#pragma unroll
        for (int s = 0; s < 2; ++s)
            a2[s] = *(const bf16x8*)(&wm_lds[il * 64 + (((4 * s + g) ^ (il & 7)) << 3)]);
    }
#pragma unroll
    for (int nd = 0; nd < 4; ++nd) {
        f32x4 acc = {0.f, 0.f, 0.f, 0.f};
        acc = __builtin_amdgcn_mfma_f32_16x16x32_bf16(a2[0], xfrag[nd][0], acc, 0, 0, 0);
        acc = __builtin_amdgcn_mfma_f32_16x16x32_bf16(a2[1], xfrag[nd][1], acc, 0, 0, 0);
        int d = 16 * nd + c;
        float* pp = part + (((size_t)u * NB + b) * ND + d) * NS + i0 + 16 * wv + 4 * g;
        *(f32x4*)pp = acc;
    }

    // --- last-block-reduces epilogue (threadFenceReduction idiom) ---
    __threadfence();        // make this block's part stores device-visible
    __syncthreads();
    if (t == 0) {
        int old = atomicAdd(&cnt[b * 8 + ti], 1);
        is_last = (old == 7 - ti);      // 8-ti contributors for this (b,ti)
    }
    __syncthreads();
    if (!is_last) return;
    __threadfence();        // acquire: see all contributors' part stores

#pragma unroll
    for (int e = 0; e < 4; ++e) {
        int idx = t + 256 * e;          // 0..1023 = d*16 + iq
        int d = idx >> 4, iq = idx & 15;
        float r0 = rs[b * ND + d];
        f32x4 vsum = {r0, r0, r0, r0};
        for (int up = ti; up < 8; ++up) {
            f32x4 pv = *(const f32x4*)&part[(((size_t)up * NB + b) * ND + d) * NS + i0 + 4 * iq];
            vsum[0] += pv[0]; vsum[1] += pv[1]; vsum[2] += pv[2]; vsum[3] += pv[3];
        }
        *(f32x4*)&out[((size_t)b * ND + d) * NS + i0 + 4 * iq] = vsum;
    }
}

extern "C" void kernel_launch(void* const* d_in, const int* in_sizes, int n_in,
                              void* d_out, int out_size, void* d_ws, size_t ws_size,
                              hipStream_t stream) {
    const float* x = (const float*)d_in[0];
    const float* W = (const float*)d_in[1];
    float* out = (float*)d_out;

    unsigned short* a_bf = (unsigned short*)d_ws;            // 512 KB
    unsigned short* b_bf = a_bf + (size_t)NB * NS * ND;      // 512 KB
    unsigned short* x_bf = b_bf + (size_t)NB * NS * ND;      // 512 KB
    float* na_p = (float*)(x_bf + (size_t)NB * NS * ND);     // 16 KB
    float* nb_p = na_p + NB * NS;                            // 16 KB
    float* rs_p = nb_p + NB * NS;                            // 2 KB
    float* part = rs_p + NB * ND;                            // 8 MB
    int*   cnt  = (int*)(part + (size_t)8 * NB * ND * NS);   // 256 B

    k_ab<<<dim3(NS / JT + 8, NB), dim3(256), 0, stream>>>(x, W, a_bf, b_bf, na_p, nb_p, x_bf, rs_p, cnt);
    k_c <<<dim3(36, NB),          dim3(256), 0, stream>>>(x_bf, a_bf, b_bf, na_p, nb_p, rs_p, part, cnt, out);
}

// Round 10
// 19.856 us; speedup vs baseline: 4.0568x; 4.0568x over previous
//
#include <hip/hip_runtime.h>
#include <math.h>

#define NB 8
#define ND 64
#define NS 512

typedef __attribute__((ext_vector_type(8))) short bf16x8;
typedef __attribute__((ext_vector_type(4))) float f32x4;
typedef __attribute__((ext_vector_type(4))) unsigned short us4;
typedef __attribute__((ext_vector_type(8))) unsigned short us8;

__device__ __forceinline__ unsigned short f2bf(float f) {
    unsigned int u = __float_as_uint(f);
    unsigned int r = (u + 0x7FFFu + ((u >> 16) & 1u)) >> 16;   // RNE
    return (unsigned short)r;
}

#define MFMA __builtin_amdgcn_mfma_f32_16x16x32_bf16

// ---------------------------------------------------------------------------
// Kernel 1: fully self-contained part-tile compute. Block (b, v=(ti,u) with
// ti<=u), 256 threads. Stages W + x-tiles, recomputes a/b rows via MFMA
// (R7-validated), then GEMM1 -> wm -> GEMM2 -> disjoint part stores (R5).
// ---------------------------------------------------------------------------
__global__ __launch_bounds__(256) void k_part(const float* __restrict__ x,
                                              const float* __restrict__ W,
                                              float* __restrict__ part) {
    __shared__ __align__(16) unsigned short WT[128 * 64];   // [n][d] swz (Ww|Wh cols)
    __shared__ __align__(16) unsigned short xwd_i[64 * 64]; // [i_loc][d] swz
    __shared__ __align__(16) unsigned short xwd_u[64 * 64]; // [w_loc][d] swz
    __shared__ __align__(16) unsigned short xdw[64 * 64];   // [d][w_loc] swz
    __shared__ __align__(16) unsigned short alds[64 * 64];  // [i_loc][k] swz
    __shared__ __align__(16) unsigned short blds[64 * 64];  // [w_loc][k] swz
    __shared__ __align__(16) unsigned short wmb[64 * 64];   // [i_loc][w_loc] swz
    __shared__ float na_lds[64], nb_lds[64];

    int b = blockIdx.y;
    int v = blockIdx.x;
    int u = 0;
    while ((u + 1) * (u + 2) / 2 <= v) ++u;   // w-tile
    int ti = v - u * (u + 1) / 2;             // i-tile (ti <= u)
    int i0 = ti * 64, w0 = u * 64;

    int t = threadIdx.x;
    int lane = t & 63, wv = t >> 6, c = lane & 15, g = lane >> 4, c7 = c & 7;

    // ---- stage WT (both halves, bf16, swizzled) ----
    {
        int n = t & 127, half = t >> 7;
#pragma unroll
        for (int p = 0; p < 4; ++p) {
            int dg = half * 4 + p;
            us8 h;
#pragma unroll
            for (int dd = 0; dd < 8; ++dd)
                h[dd] = f2bf(W[(size_t)(dg * 8 + dd) * ND + (n & 63) + ((n >> 6) * (ND * ND))]);
            *(us8*)&WT[n * 64 + ((dg ^ (n & 7)) << 3)] = h;
        }
    }
    // ---- stage xwd_i / xwd_u ([row][d], coalesced row-reads) ----
    {
        int wl = t & 63, w2 = t >> 6;
#pragma unroll
        for (int j = 0; j < 2; ++j) {
            int dblk = 2 * w2 + j;
            us8 hi, hu;
#pragma unroll
            for (int e = 0; e < 8; ++e) {
                int d = 8 * dblk + e;
                const float* base = x + ((size_t)(b * ND) + d) * NS;
                hi[e] = f2bf(base[i0 + wl]);
                hu[e] = f2bf(base[w0 + wl]);
            }
            *(us8*)&xwd_i[wl * 64 + ((dblk ^ (wl & 7)) << 3)] = hi;
            *(us8*)&xwd_u[wl * 64 + ((dblk ^ (wl & 7)) << 3)] = hu;
        }
    }
    // ---- stage xdw ([d][w_loc], coalesced f32x4 reads) ----
#pragma unroll
    for (int q = 0; q < 2; ++q) {
        int e = t + 256 * q;
        int d = e >> 3, wc = e & 7;
        const float4* p4 = (const float4*)(x + ((size_t)(b * ND) + d) * NS + w0 + 8 * wc);
        float4 v0 = p4[0], v1 = p4[1];
        us8 h;
        h[0] = f2bf(v0.x); h[1] = f2bf(v0.y); h[2] = f2bf(v0.z); h[3] = f2bf(v0.w);
        h[4] = f2bf(v1.x); h[5] = f2bf(v1.y); h[6] = f2bf(v1.z); h[7] = f2bf(v1.w);
        *(us8*)&xdw[d * 64 + ((wc ^ (d & 7)) << 3)] = h;
    }
    __syncthreads();

    // ---- a-GEMM and b-GEMM (R7-validated patterns) ----
    {
        f32x4 aacc[4] = {{0,0,0,0},{0,0,0,0},{0,0,0,0},{0,0,0,0}};
        f32x4 bacc[4] = {{0,0,0,0},{0,0,0,0},{0,0,0,0},{0,0,0,0}};
#pragma unroll
        for (int ks = 0; ks < 2; ++ks) {
            int row = 16 * wv + c;
            bf16x8 Pi = *(const bf16x8*)&xwd_i[row * 64 + (((4 * ks + g) ^ c7) << 3)];
            bf16x8 Pu = *(const bf16x8*)&xwd_u[row * 64 + (((4 * ks + g) ^ c7) << 3)];
#pragma unroll
            for (int qb = 0; qb < 4; ++qb) {
                bf16x8 Qw = *(const bf16x8*)&WT[(16 * qb + c) * 64 + (((4 * ks + g) ^ c7) << 3)];
                bf16x8 Qh = *(const bf16x8*)&WT[(64 + 16 * qb + c) * 64 + (((4 * ks + g) ^ c7) << 3)];
                aacc[qb] = MFMA(Pi, Qw, aacc[qb], 0, 0, 0);
                bacc[qb] = MFMA(Pu, Qh, bacc[qb], 0, 0, 0);
            }
        }
        // norms (f32, pre-rounding)
#pragma unroll
        for (int r = 0; r < 4; ++r) {
            float sa = aacc[0][r] * aacc[0][r] + aacc[1][r] * aacc[1][r]
                     + aacc[2][r] * aacc[2][r] + aacc[3][r] * aacc[3][r];
            float sb = bacc[0][r] * bacc[0][r] + bacc[1][r] * bacc[1][r]
                     + bacc[2][r] * bacc[2][r] + bacc[3][r] * bacc[3][r];
            sa += __shfl_xor(sa, 1, 64); sa += __shfl_xor(sa, 2, 64);
            sa += __shfl_xor(sa, 4, 64); sa += __shfl_xor(sa, 8, 64);
            sb += __shfl_xor(sb, 1, 64); sb += __shfl_xor(sb, 2, 64);
            sb += __shfl_xor(sb, 4, 64); sb += __shfl_xor(sb, 8, 64);
            if (c == 0) {
                na_lds[16 * wv + 4 * g + r] = sa;
                nb_lds[16 * wv + 4 * g + r] = sb;
            }
        }
        // bf16 stores to alds/blds
#pragma unroll
        for (int qb = 0; qb < 4; ++qb)
#pragma unroll
            for (int r = 0; r < 4; ++r) {
                int row = 16 * wv + 4 * g + r, k = 16 * qb + c;
                int off = row * 64 + (((k >> 3) ^ (row & 7)) << 3) + (k & 7);
                alds[off] = f2bf(aacc[qb][r]);
                blds[off] = f2bf(bacc[qb][r]);
            }
    }
    __syncthreads();

    // ---- GEMM1: S[w][i] = b·a^T ; wm = masked -sqrt(na+nb+2S) ----
    {
        int wrow = 16 * wv + c;
        bf16x8 P0 = *(const bf16x8*)&blds[wrow * 64 + ((g ^ c7) << 3)];
        bf16x8 P1 = *(const bf16x8*)&blds[wrow * 64 + (((4 + g) ^ c7) << 3)];
        float nbv[4];
#pragma unroll
        for (int r = 0; r < 4; ++r) nbv[r] = nb_lds[16 * wv + 4 * g + r];
        int wbase = w0 + 16 * wv + 4 * g;
#pragma unroll
        for (int n = 0; n < 4; ++n) {
            int arow = 16 * n + c;
            f32x4 a1 = {0.f, 0.f, 0.f, 0.f};
            bf16x8 Q0 = *(const bf16x8*)&alds[arow * 64 + ((g ^ c7) << 3)];
            bf16x8 Q1 = *(const bf16x8*)&alds[arow * 64 + (((4 + g) ^ c7) << 3)];
            a1 = MFMA(P0, Q0, a1, 0, 0, 0);
            a1 = MFMA(P1, Q1, a1, 0, 0, 0);
            float navv = na_lds[arow];
            int i_glob = i0 + arow;
            us4 pk;
#pragma unroll
            for (int r = 0; r < 4; ++r) {
                float s2v = navv + nbv[r] + 2.f * a1[r];
                float val = (i_glob <= wbase + r) ? -sqrtf(fmaxf(s2v, 0.f)) : 0.f;
                pk[r] = f2bf(val);
            }
            int wblk = 2 * wv + (g >> 1);
            *(us4*)&wmb[arow * 64 + ((wblk ^ (arow & 7)) << 3) + 4 * (g & 1)] = pk;
        }
    }
    __syncthreads();

    // ---- GEMM2: part[u][b][d][i-tile] = wm·x^T, disjoint f32x4 stores ----
    {
        int il = 16 * wv + c;
        bf16x8 a20 = *(const bf16x8*)&wmb[il * 64 + ((g ^ c7) << 3)];
        bf16x8 a21 = *(const bf16x8*)&wmb[il * 64 + (((4 + g) ^ c7) << 3)];
#pragma unroll
        for (int nd = 0; nd < 4; ++nd) {
            int d = 16 * nd + c;
            bf16x8 q0 = *(const bf16x8*)&xdw[d * 64 + ((g ^ c7) << 3)];
            bf16x8 q1 = *(const bf16x8*)&xdw[d * 64 + (((4 + g) ^ c7) << 3)];
            f32x4 acc = {0.f, 0.f, 0.f, 0.f};
            acc = MFMA(a20, q0, acc, 0, 0, 0);
            acc = MFMA(a21, q1, acc, 0, 0, 0);
            float* pp = part + (((size_t)u * NB + b) * ND + d) * NS + i0 + 16 * wv + 4 * g;
            *(f32x4*)pp = acc;
        }
    }
}

// ---------------------------------------------------------------------------
// Kernel 2: out[b,d,i] = rowsum(x[b,d,:]) + sum_{u >= i>>6} part[u][b][d][i]
// rs computed inline (no producer dependency beyond part).
// ---------------------------------------------------------------------------
__global__ __launch_bounds__(256) void k_red(const float* __restrict__ x,
                                             const float* __restrict__ part,
                                             float* __restrict__ out) {
    __shared__ float red[4];
    int b = blockIdx.y, d = blockIdx.x, t = threadIdx.x;
    const float* xr = x + ((size_t)b * ND + d) * NS;

    float s = xr[t] + xr[t + 256];
#pragma unroll
    for (int m = 32; m >= 1; m >>= 1) s += __shfl_xor(s, m, 64);
    if ((t & 63) == 0) red[t >> 6] = s;
    __syncthreads();
    float rs = red[0] + red[1] + red[2] + red[3];

#pragma unroll
    for (int q = 0; q < 2; ++q) {
        int i  = t + q * 256;
        int it = i >> 6;
        float vv = rs;
#pragma unroll
        for (int u = 0; u < 8; ++u) {
            if (u >= it)
                vv += part[(((size_t)u * NB + b) * ND + d) * NS + i];
        }
        out[((size_t)b * ND + d) * NS + i] = vv;
    }
}

extern "C" void kernel_launch(void* const* d_in, const int* in_sizes, int n_in,
                              void* d_out, int out_size, void* d_ws, size_t ws_size,
                              hipStream_t stream) {
    const float* x = (const float*)d_in[0];
    const float* W = (const float*)d_in[1];
    float* out  = (float*)d_out;
    float* part = (float*)d_ws;                 // 8 MB

    k_part<<<dim3(36, NB), dim3(256), 0, stream>>>(x, W, part);
    k_red <<<dim3(ND, NB), dim3(256), 0, stream>>>(x, part, out);
}

// Round 11
// 18.653 us; speedup vs baseline: 4.3184x; 1.0645x over previous
//
#include <hip/hip_runtime.h>
#include <math.h>

#define NB 8
#define ND 64
#define NS 512

typedef __attribute__((ext_vector_type(8))) short bf16x8;
typedef __attribute__((ext_vector_type(4))) float f32x4;
typedef __attribute__((ext_vector_type(4))) unsigned short us4;
typedef __attribute__((ext_vector_type(8))) unsigned short us8;

__device__ __forceinline__ unsigned short f2bf(float f) {
    unsigned int u = __float_as_uint(f);
    unsigned int r = (u + 0x7FFFu + ((u >> 16) & 1u)) >> 16;   // RNE
    return (unsigned short)r;
}

#define MFMA __builtin_amdgcn_mfma_f32_16x16x32_bf16

// ---------------------------------------------------------------------------
// Kernel 1: self-contained part-tile compute. Block (b, v=(ti,u), ti<=u),
// 256 threads, 2 blocks/CU co-resident. Batched staging -> a/b MFMA recompute
// -> GEMM1 -> wm -> GEMM2 -> disjoint part stores. (R10-validated phases.)
// ---------------------------------------------------------------------------
__global__ __launch_bounds__(256, 2) void k_part(const float* __restrict__ x,
                                                 const float* __restrict__ W,
                                                 float* __restrict__ part) {
    __shared__ __align__(16) unsigned short WT[128 * 64];   // [n][d] swz (Ww|Wh cols)
    __shared__ __align__(16) unsigned short xwd_i[64 * 64]; // [i_loc][d] swz
    __shared__ __align__(16) unsigned short xwd_u[64 * 64]; // [w_loc][d] swz
    __shared__ __align__(16) unsigned short xdw[64 * 64];   // [d][w_loc] swz
    __shared__ __align__(16) unsigned short alds[64 * 64];  // [i_loc][k] swz
    __shared__ __align__(16) unsigned short blds[64 * 64];  // [w_loc][k] swz
    __shared__ __align__(16) unsigned short wmb[64 * 64];   // [i_loc][w_loc] swz
    __shared__ float na_lds[64], nb_lds[64];

    int b = blockIdx.y;
    int v = blockIdx.x;
    int u = 0;
    while ((u + 1) * (u + 2) / 2 <= v) ++u;   // w-tile
    int ti = v - u * (u + 1) / 2;             // i-tile (ti <= u)
    int i0 = ti * 64, w0 = u * 64;

    int t = threadIdx.x;
    int lane = t & 63, wv = t >> 6, c = lane & 15, g = lane >> 4, c7 = c & 7;

    // ======== staging batch 1: all x loads hoisted into registers ========
    int wl = t & 63, w2 = t >> 6;
    float xi_[16], xu_[16];
#pragma unroll
    for (int j = 0; j < 2; ++j)
#pragma unroll
        for (int e = 0; e < 8; ++e) {
            int d = 8 * (2 * w2 + j) + e;
            const float* base = x + ((size_t)(b * ND) + d) * NS;
            xi_[8 * j + e] = base[i0 + wl];
            xu_[8 * j + e] = base[w0 + wl];
        }
    float4 xd_[4];
#pragma unroll
    for (int q = 0; q < 2; ++q) {
        int e = t + 256 * q;
        int d = e >> 3, wc = e & 7;
        const float4* p4 = (const float4*)(x + ((size_t)(b * ND) + d) * NS + w0 + 8 * wc);
        xd_[2 * q]     = p4[0];
        xd_[2 * q + 1] = p4[1];
    }
    // convert + LDS writes for batch 1
#pragma unroll
    for (int j = 0; j < 2; ++j) {
        int dblk = 2 * w2 + j;
        us8 hi, hu;
#pragma unroll
        for (int e = 0; e < 8; ++e) {
            hi[e] = f2bf(xi_[8 * j + e]);
            hu[e] = f2bf(xu_[8 * j + e]);
        }
        *(us8*)&xwd_i[wl * 64 + ((dblk ^ (wl & 7)) << 3)] = hi;
        *(us8*)&xwd_u[wl * 64 + ((dblk ^ (wl & 7)) << 3)] = hu;
    }
#pragma unroll
    for (int q = 0; q < 2; ++q) {
        int e = t + 256 * q;
        int d = e >> 3, wc = e & 7;
        float4 v0 = xd_[2 * q], v1 = xd_[2 * q + 1];
        us8 h;
        h[0] = f2bf(v0.x); h[1] = f2bf(v0.y); h[2] = f2bf(v0.z); h[3] = f2bf(v0.w);
        h[4] = f2bf(v1.x); h[5] = f2bf(v1.y); h[6] = f2bf(v1.z); h[7] = f2bf(v1.w);
        *(us8*)&xdw[d * 64 + ((wc ^ (d & 7)) << 3)] = h;
    }
    // ======== staging batch 2: W loads -> WT ========
    {
        int n = t & 127, half = t >> 7;
        float wv_[32];
#pragma unroll
        for (int p = 0; p < 4; ++p)
#pragma unroll
            for (int dd = 0; dd < 8; ++dd) {
                int dg = half * 4 + p;
                wv_[8 * p + dd] =
                    W[(size_t)(dg * 8 + dd) * ND + (n & 63) + ((n >> 6) * (ND * ND))];
            }
#pragma unroll
        for (int p = 0; p < 4; ++p) {
            int dg = half * 4 + p;
            us8 h;
#pragma unroll
            for (int dd = 0; dd < 8; ++dd) h[dd] = f2bf(wv_[8 * p + dd]);
            *(us8*)&WT[n * 64 + ((dg ^ (n & 7)) << 3)] = h;
        }
    }
    __syncthreads();

    // ---- a-GEMM and b-GEMM (validated) ----
    {
        f32x4 aacc[4] = {{0,0,0,0},{0,0,0,0},{0,0,0,0},{0,0,0,0}};
        f32x4 bacc[4] = {{0,0,0,0},{0,0,0,0},{0,0,0,0},{0,0,0,0}};
#pragma unroll
        for (int ks = 0; ks < 2; ++ks) {
            int row = 16 * wv + c;
            bf16x8 Pi = *(const bf16x8*)&xwd_i[row * 64 + (((4 * ks + g) ^ c7) << 3)];
            bf16x8 Pu = *(const bf16x8*)&xwd_u[row * 64 + (((4 * ks + g) ^ c7) << 3)];
#pragma unroll
            for (int qb = 0; qb < 4; ++qb) {
                bf16x8 Qw = *(const bf16x8*)&WT[(16 * qb + c) * 64 + (((4 * ks + g) ^ c7) << 3)];
                bf16x8 Qh = *(const bf16x8*)&WT[(64 + 16 * qb + c) * 64 + (((4 * ks + g) ^ c7) << 3)];
                aacc[qb] = MFMA(Pi, Qw, aacc[qb], 0, 0, 0);
                bacc[qb] = MFMA(Pu, Qh, bacc[qb], 0, 0, 0);
            }
        }
#pragma unroll
        for (int r = 0; r < 4; ++r) {
            float sa = aacc[0][r] * aacc[0][r] + aacc[1][r] * aacc[1][r]
                     + aacc[2][r] * aacc[2][r] + aacc[3][r] * aacc[3][r];
            float sb = bacc[0][r] * bacc[0][r] + bacc[1][r] * bacc[1][r]
                     + bacc[2][r] * bacc[2][r] + bacc[3][r] * bacc[3][r];
            sa += __shfl_xor(sa, 1, 64); sa += __shfl_xor(sa, 2, 64);
            sa += __shfl_xor(sa, 4, 64); sa += __shfl_xor(sa, 8, 64);
            sb += __shfl_xor(sb, 1, 64); sb += __shfl_xor(sb, 2, 64);
            sb += __shfl_xor(sb, 4, 64); sb += __shfl_xor(sb, 8, 64);
            if (c == 0) {
                na_lds[16 * wv + 4 * g + r] = sa;
                nb_lds[16 * wv + 4 * g + r] = sb;
            }
        }
#pragma unroll
        for (int qb = 0; qb < 4; ++qb)
#pragma unroll
            for (int r = 0; r < 4; ++r) {
                int row = 16 * wv + 4 * g + r, k = 16 * qb + c;
                int off = row * 64 + (((k >> 3) ^ (row & 7)) << 3) + (k & 7);
                alds[off] = f2bf(aacc[qb][r]);
                blds[off] = f2bf(bacc[qb][r]);
            }
    }
    __syncthreads();

    // ---- GEMM1: S[w][i] = b·a^T ; wm = masked -sqrt(na+nb+2S) ----
    {
        int wrow = 16 * wv + c;
        bf16x8 P0 = *(const bf16x8*)&blds[wrow * 64 + ((g ^ c7) << 3)];
        bf16x8 P1 = *(const bf16x8*)&blds[wrow * 64 + (((4 + g) ^ c7) << 3)];
        float nbv[4];
#pragma unroll
        for (int r = 0; r < 4; ++r) nbv[r] = nb_lds[16 * wv + 4 * g + r];
        int wbase = w0 + 16 * wv + 4 * g;
#pragma unroll
        for (int n = 0; n < 4; ++n) {
            int arow = 16 * n + c;
            f32x4 a1 = {0.f, 0.f, 0.f, 0.f};
            bf16x8 Q0 = *(const bf16x8*)&alds[arow * 64 + ((g ^ c7) << 3)];
            bf16x8 Q1 = *(const bf16x8*)&alds[arow * 64 + (((4 + g) ^ c7) << 3)];
            a1 = MFMA(P0, Q0, a1, 0, 0, 0);
            a1 = MFMA(P1, Q1, a1, 0, 0, 0);
            float navv = na_lds[arow];
            int i_glob = i0 + arow;
            us4 pk;
#pragma unroll
            for (int r = 0; r < 4; ++r) {
                float s2v = navv + nbv[r] + 2.f * a1[r];
                float val = (i_glob <= wbase + r) ? -sqrtf(fmaxf(s2v, 0.f)) : 0.f;
                pk[r] = f2bf(val);
            }
            int wblk = 2 * wv + (g >> 1);
            *(us4*)&wmb[arow * 64 + ((wblk ^ (arow & 7)) << 3) + 4 * (g & 1)] = pk;
        }
    }
    __syncthreads();

    // ---- GEMM2: part[u][b][d][i-tile] = wm·x^T, disjoint f32x4 stores ----
    {
        int il = 16 * wv + c;
        bf16x8 a20 = *(const bf16x8*)&wmb[il * 64 + ((g ^ c7) << 3)];
        bf16x8 a21 = *(const bf16x8*)&wmb[il * 64 + (((4 + g) ^ c7) << 3)];
#pragma unroll
        for (int nd = 0; nd < 4; ++nd) {
            int d = 16 * nd + c;
            bf16x8 q0 = *(const bf16x8*)&xdw[d * 64 + ((g ^ c7) << 3)];
            bf16x8 q1 = *(const bf16x8*)&xdw[d * 64 + (((4 + g) ^ c7) << 3)];
            f32x4 acc = {0.f, 0.f, 0.f, 0.f};
            acc = MFMA(a20, q0, acc, 0, 0, 0);
            acc = MFMA(a21, q1, acc, 0, 0, 0);
            float* pp = part + (((size_t)u * NB + b) * ND + d) * NS + i0 + 16 * wv + 4 * g;
            *(f32x4*)pp = acc;
        }
    }
}

// ---------------------------------------------------------------------------
// Kernel 2: out[b,d,i] = rowsum(x[b,d,:]) + sum_{u >= i>>6} part[u][b][d][i]
// 512 blocks x 128 threads, all-f32x4.
// ---------------------------------------------------------------------------
__global__ __launch_bounds__(128) void k_red(const float* __restrict__ x,
                                             const float* __restrict__ part,
                                             float* __restrict__ out) {
    __shared__ float red[2];
    int b = blockIdx.y, d = blockIdx.x, t = threadIdx.x;   // t < 128
    const float* xr = x + ((size_t)b * ND + d) * NS;

    float4 xv = *(const float4*)(xr + 4 * t);
    float s = xv.x + xv.y + xv.z + xv.w;
#pragma unroll
    for (int m = 32; m >= 1; m >>= 1) s += __shfl_xor(s, m, 64);
    if ((t & 63) == 0) red[t >> 6] = s;
    __syncthreads();
    float rs = red[0] + red[1];

    int it = t >> 4;                      // (4t)>>6
    f32x4 vv = {rs, rs, rs, rs};
#pragma unroll
    for (int u = 0; u < 8; ++u) {
        if (u >= it) {
            f32x4 pv = *(const f32x4*)&part[(((size_t)u * NB + b) * ND + d) * NS + 4 * t];
            vv[0] += pv[0]; vv[1] += pv[1]; vv[2] += pv[2]; vv[3] += pv[3];
        }
    }
    *(f32x4*)&out[((size_t)b * ND + d) * NS + 4 * t] = vv;
}

extern "C" void kernel_launch(void* const* d_in, const int* in_sizes, int n_in,
                              void* d_out, int out_size, void* d_ws, size_t ws_size,
                              hipStream_t stream) {
    const float* x = (const float*)d_in[0];
    const float* W = (const float*)d_in[1];
    float* out  = (float*)d_out;
    float* part = (float*)d_ws;                 // 8 MB

    k_part<<<dim3(36, NB), dim3(256), 0, stream>>>(x, W, part);
    k_red <<<dim3(ND, NB), dim3(128), 0, stream>>>(x, part, out);
}